// Round 9
// baseline (303.592 us; speedup 1.0000x reference)
//
#include <hip/hip_runtime.h>
#include <math.h>

#define B_  2
#define D_  1536
#define L_  2048
#define N_  16
#define NH  8                 // states per half-wave
#define LC  128               // chunk length along L (32 segs x 4 elems)
#define NCHUNK (L_ / LC)      // 16
#define NCH (B_ * D_)         // 3072 channels
#define LOG2E 1.4426950408889634f
#define LN2   0.6931471805599453f

typedef float f4 __attribute__((ext_vector_type(4)));
typedef float f8 __attribute__((ext_vector_type(8)));

__device__ __forceinline__ float exp2f_(float v) { return __builtin_amdgcn_exp2f(v); }
__device__ __forceinline__ float log2f_(float v) { return __builtin_amdgcn_logf(v); }
__device__ __forceinline__ float rcpf_(float v)  { return __builtin_amdgcn_rcpf(v); }

__device__ __forceinline__ float softplus_f(float v) {
    float t = exp2f_(v * LOG2E);                   // e^v
    float r = LN2 * log2f_(1.0f + t);              // ln(1+e^v)
    return (v > 20.0f) ? v : r;
}
__device__ __forceinline__ float rdlane(float v, int l) {
    return __int_as_float(__builtin_amdgcn_readlane(__float_as_int(v), l));
}

// DPP move with explicit identity for invalid/masked lanes (bound_ctrl=false
// and masked rows both produce `old`).
#define DPP_ROW_SHR(N) (0x110 + (N))
#define DPP_ROW_BCAST15 0x142
#define DPP_WAVE_SHR1   0x138
template<int CTRL, int RMASK>
__device__ __forceinline__ float updpp(float old, float v) {
    return __int_as_float(__builtin_amdgcn_update_dpp(
        __float_as_int(old), __float_as_int(v), CTRL, RMASK, 0xF, false));
}

// One wave (= one 64-thread block) per channel. lane=(g,s): g=lane>>5 owns 8
// of 16 states, s=lane&31 owns a 4-elem L-segment of each 128-chunk.
// No LDS/barriers. Per-state f4 computation (no cross-register transposes).
// delta/x/z/B register-prefetched one chunk ahead; C loaded mid-chunk (its
// latency hides under the DPP scan+fold). Width-32 scan on the VALU pipe via
// DPP row_shr 1/2/4/8 + row_bcast15 (row_mask=0xA: rows 1,3 only — writing
// rows 0/2 would leak g=0's total into g=1's scan start). Carry broadcast via
// v_readlane pair (no DS op on the serial chain). All state SSA (no scratch).
__global__ __launch_bounds__(64, 3)
void ssm_scan_kernel(const float* __restrict__ x,
                     const float* __restrict__ delta,
                     const float* __restrict__ A,
                     const float* __restrict__ Bm,
                     const float* __restrict__ Cm,
                     const float* __restrict__ Dv,
                     const float* __restrict__ z,
                     const float* __restrict__ dbias,
                     float* __restrict__ out)
{
    const int lane = threadIdx.x;      // 0..63
    const int s    = lane & 31;
    const int g    = lane >> 5;
    const int ch   = blockIdx.x;       // one channel per wave
    const int b    = ch / D_;
    const int d    = ch - b * D_;

    const float bias = dbias[d];
    const float Dd   = Dv[d];

    const float* Ab = A + d * N_ + NH * g;
    f8 A2;
#pragma unroll
    for (int i = 0; i < NH; ++i) A2[i] = Ab[i] * LOG2E;

    const float* Bp = Bm + (size_t)b * (N_ * L_) + (size_t)(NH * g) * L_;
    const float* Cp = Cm + (size_t)b * (N_ * L_) + (size_t)(NH * g) * L_;
    const size_t chbase = (size_t)ch * L_;

    f8 carry = {0.0f,0.0f,0.0f,0.0f,0.0f,0.0f,0.0f,0.0f};

    // ---- prefetch chunk 0: delta/x/z + all B rows ----
    f4 pD = *(const f4*)(delta + chbase + s * 4);
    f4 pX = *(const f4*)(x     + chbase + s * 4);
    f4 pZ = *(const f4*)(z     + chbase + s * 4);
#define PF_B(i) f4 pB##i = *(const f4*)(Bp + i * L_ + s * 4);
    PF_B(0) PF_B(1) PF_B(2) PF_B(3) PF_B(4) PF_B(5) PF_B(6) PF_B(7)

    for (int c = 0; c < NCHUNK; ++c) {
        const int o = c * LC + s * 4;

        // ---- consume prefetched values ----
        f4 dv = pD, xv = pX, zv = pZ;
#define CP_B(i) f4 B##i = pB##i;
        CP_B(0) CP_B(1) CP_B(2) CP_B(3) CP_B(4) CP_B(5) CP_B(6) CP_B(7)

        // ---- issue next chunk's prefetch (overlaps all compute below) ----
        if (c + 1 < NCHUNK) {
            const int o2 = o + LC;
            pD = *(const f4*)(delta + chbase + o2);
            pX = *(const f4*)(x     + chbase + o2);
            pZ = *(const f4*)(z     + chbase + o2);
#define PF_B2(i) pB##i = *(const f4*)(Bp + i * L_ + o2);
            PF_B2(0) PF_B2(1) PF_B2(2) PF_B2(3) PF_B2(4) PF_B2(5) PF_B2(6) PF_B2(7)
        }

        // ---- dt / u ----
        float dt0 = softplus_f(dv.x + bias);
        float dt1 = softplus_f(dv.y + bias);
        float dt2 = softplus_f(dv.z + bias);
        float dt3 = softplus_f(dv.w + bias);
        f4 uv = { dt0 * xv.x, dt1 * xv.y, dt2 * xv.z, dt3 * xv.w };

        // ---- per-state: e (f4 over j), uB, local 4-elem scan, P by muls ----
        f8 S, P;
#define STATE1(i) \
        f4 e##i; \
        e##i.x = exp2f_(dt0 * A2[i]); e##i.y = exp2f_(dt1 * A2[i]); \
        e##i.z = exp2f_(dt2 * A2[i]); e##i.w = exp2f_(dt3 * A2[i]); \
        f4 uB##i = uv * B##i; \
        { float acc = uB##i.x; \
          acc = fmaf(e##i.y, acc, uB##i.y); \
          acc = fmaf(e##i.z, acc, uB##i.z); \
          acc = fmaf(e##i.w, acc, uB##i.w); \
          S[i] = acc; \
          P[i] = (e##i.x * e##i.y) * (e##i.z * e##i.w); }
        STATE1(0) STATE1(1) STATE1(2) STATE1(3)
        STATE1(4) STATE1(5) STATE1(6) STATE1(7)

        // ---- C loads: issued here so L2 latency hides under scan+fold ----
#define LD_C(i) f4 C##i = *(const f4*)(Cp + i * L_ + o);
        LD_C(0) LD_C(1) LD_C(2) LD_C(3) LD_C(4) LD_C(5) LD_C(6) LD_C(7)

        // ---- width-32 inclusive scan of (P,S), all DPP/VALU ----
#define SCAN_STEP(CTRL, RMASK) \
        { \
            _Pragma("unroll") \
            for (int i = 0; i < NH; ++i) { \
                float Pp = updpp<CTRL, RMASK>(1.0f, P[i]); \
                float Sp = updpp<CTRL, RMASK>(0.0f, S[i]); \
                S[i] = fmaf(Sp, P[i], S[i]);   /* uses pre-update P */ \
                P[i] = P[i] * Pp; \
            } \
        }
        SCAN_STEP(DPP_ROW_SHR(1), 0xF)
        SCAN_STEP(DPP_ROW_SHR(2), 0xF)
        SCAN_STEP(DPP_ROW_SHR(4), 0xF)
        SCAN_STEP(DPP_ROW_SHR(8), 0xF)
        SCAN_STEP(DPP_ROW_BCAST15, 0xA)  // rows 1,3 only; rows 0,2 keep neutral

        // ---- fold chunk carry; h entering this lane's segment ----
        f8 h;
#pragma unroll
        for (int i = 0; i < NH; ++i) {
            float hinc = fmaf(carry[i], P[i], S[i]);        // true inclusive state
            float hup  = updpp<DPP_WAVE_SHR1, 0xF>(0.0f, hinc); // lane n <- n-1
            h[i] = (s == 0) ? carry[i] : hup;               // fixes lanes 0 and 32
            float c0 = rdlane(hinc, 31);                    // g=0 half total
            float c1 = rdlane(hinc, 63);                    // g=1 half total
            carry[i] = g ? c1 : c0;                         // no DS on the chain
        }

        // ---- pass 2: recurrence from h (reuse e, uB); y_j = sum_i h*C ----
        float y0 = 0.0f, y1 = 0.0f, y2 = 0.0f, y3 = 0.0f;
#define STATE2(i) { float hh = h[i]; \
        hh = fmaf(e##i.x, hh, uB##i.x); y0 = fmaf(hh, C##i.x, y0); \
        hh = fmaf(e##i.y, hh, uB##i.y); y1 = fmaf(hh, C##i.y, y1); \
        hh = fmaf(e##i.z, hh, uB##i.z); y2 = fmaf(hh, C##i.z, y2); \
        hh = fmaf(e##i.w, hh, uB##i.w); y3 = fmaf(hh, C##i.w, y3); }
        STATE2(0) STATE2(1) STATE2(2) STATE2(3)
        STATE2(4) STATE2(5) STATE2(6) STATE2(7)

        // ---- combine the two state-halves; epilogue; half-wave store ----
        y0 += __shfl_xor(y0, 32, 64);
        y1 += __shfl_xor(y1, 32, 64);
        y2 += __shfl_xor(y2, 32, 64);
        y3 += __shfl_xor(y3, 32, 64);
        if (g == 0) {
            float s0 = rcpf_(1.0f + exp2f_(-zv.x * LOG2E));
            float s1 = rcpf_(1.0f + exp2f_(-zv.y * LOG2E));
            float s2 = rcpf_(1.0f + exp2f_(-zv.z * LOG2E));
            float s3 = rcpf_(1.0f + exp2f_(-zv.w * LOG2E));
            f4 ov = { (y0 + xv.x * Dd) * (zv.x * s0),
                      (y1 + xv.y * Dd) * (zv.y * s1),
                      (y2 + xv.z * Dd) * (zv.z * s2),
                      (y3 + xv.w * Dd) * (zv.w * s3) };
            *(f4*)(out + chbase + o) = ov;
        }
    }
}

extern "C" void kernel_launch(void* const* d_in, const int* in_sizes, int n_in,
                              void* d_out, int out_size, void* d_ws, size_t ws_size,
                              hipStream_t stream) {
    const float* x     = (const float*)d_in[0];
    const float* delta = (const float*)d_in[1];
    const float* A     = (const float*)d_in[2];
    const float* Bm    = (const float*)d_in[3];
    const float* Cm    = (const float*)d_in[4];
    const float* Dv    = (const float*)d_in[5];
    const float* z     = (const float*)d_in[6];
    const float* dbias = (const float*)d_in[7];
    float* out = (float*)d_out;

    dim3 grid(NCH);    // 3072 blocks = 1 wave = 1 channel each
    dim3 block(64);
    ssm_scan_kernel<<<grid, block, 0, stream>>>(x, delta, A, Bm, Cm, Dv, z, dbias, out);
}